// Round 2
// baseline (297.456 us; speedup 1.0000x reference)
//
#include <hip/hip_runtime.h>

// Problem constants (B,H,Lq,Lkv) = (2,32,2048,2048), KEEP_RATIO=0.5, SINK=4, RECENT=64, ALPHA=0.2
#define B_   2
#define H_   32
#define BH   64
#define LQ   2048
#define LKV  2048
#define SINKN   4
#define RECENTN 64
#define MID  (LKV - SINKN - RECENTN)          // 1980
#define TOTAL_BUDGET 30592                     // (int(LKV*0.5) - 68) * H = 956*32
#define MINB 198                               // max(int(1980*0.5*0.2), 1)
#define KVCH 2
#define KVLEN (LKV / KVCH)                     // 1024 cols per block, 4 per thread (float4)

// Fused pass: scores[bh][kv] partials (sum over a q-chunk) + entropy partial sums.
// All accumulation in f64, fixed order -> deterministic.
__global__ __launch_bounds__(256) void stats_kernel(const float* __restrict__ A,
                                                    double* __restrict__ spart,
                                                    double* __restrict__ epart,
                                                    int qch) {
  const int kvc = blockIdx.x;     // 0..KVCH-1
  const int qc  = blockIdx.y;     // 0..qch-1
  const int bh  = blockIdx.z;     // 0..63
  const int t   = threadIdx.x;    // 0..255
  const int qlen = LQ / qch;
  const int kv  = kvc * KVLEN + 4 * t;
  const float4* __restrict__ p = reinterpret_cast<const float4*>(
      A + ((size_t)bh * LQ + (size_t)qc * qlen) * LKV + kv);

  double s0 = 0.0, s1 = 0.0, s2 = 0.0, s3 = 0.0, e = 0.0;
#pragma unroll 4
  for (int q = 0; q < qlen; ++q) {
    float4 w = p[(size_t)q * (LKV / 4)];
    s0 += (double)w.x; s1 += (double)w.y; s2 += (double)w.z; s3 += (double)w.w;
    float l0 = logf(w.x + 1e-8f);
    float l1 = logf(w.y + 1e-8f);
    float l2 = logf(w.z + 1e-8f);
    float l3 = logf(w.w + 1e-8f);
    e -= (double)w.x * (double)l0;
    e -= (double)w.y * (double)l1;
    e -= (double)w.z * (double)l2;
    e -= (double)w.w * (double)l3;
  }
  double* sp = spart + ((size_t)(qc * BH + bh)) * LKV + kv;
  sp[0] = s0; sp[1] = s1; sp[2] = s2; sp[3] = s3;

  __shared__ double red[256];
  red[t] = e;
  __syncthreads();
  for (int off = 128; off > 0; off >>= 1) {
    if (t < off) red[t] += red[t + off];
    __syncthreads();
  }
  if (t == 0) epart[(size_t)bh * (qch * KVCH) + qc * KVCH + kvc] = red[0];
}

// Tiny kernel: head_entropy -> budgets -> k per (b,h). Replicates _head_budgets exactly
// (round-half-even via rint, Python floor-division for diff // H).
__global__ __launch_bounds__(64) void budget_kernel(const double* __restrict__ epart,
                                                    int* __restrict__ kvals, int npart) {
  __shared__ double he[BH];
  __shared__ int bud[H_];
  const int t = threadIdx.x;  // 0..63 = bh
  double s = 0.0;
  for (int p = 0; p < npart; ++p) s += epart[(size_t)t * npart + p];
  he[t] = s / (double)LQ;     // mean over Lq of per-row entropies
  __syncthreads();
  if (t == 0) {
    for (int b = 0; b < B_; ++b) {
      double S = 0.0;
      for (int h = 0; h < H_; ++h) S += he[b * H_ + h];
      S += 1e-8;
      long long sum = 0;
      for (int h = 0; h < H_; ++h) {
        double x = he[b * H_ + h] / S * (double)TOTAL_BUDGET;
        int v = (int)rint(x);            // jnp.round = half-to-even
        if (v < MINB) v = MINB;
        bud[h] = v; sum += v;
      }
      long long diff = (long long)TOTAL_BUDGET - sum;
      long long ph = (diff >= 0) ? diff / H_ : -((-diff + H_ - 1) / H_);  // floor div
      long long rem = diff - ph * H_;     // in [0, H)
      for (int h = 0; h < H_; ++h) {
        long long v = (long long)bud[h] + ph + ((h < rem) ? 1 : 0);
        if (v < 1) v = 1;
        if (v > MID) v = MID;
        kvals[b * H_ + h] = (int)v;
      }
    }
  }
}

// Rank kernel: stable descending rank(j) = #{i<j: s_i>=s_j} + #{i>j: s_i>s_j}; keep if rank<k.
// grid = (8 j-slices, 64 bh); scores assembled in LDS (fixed-order partial sum).
// Output is int32 0/1 (harness reads the bool mask as int32!).
__global__ __launch_bounds__(256) void mask_kernel(const double* __restrict__ spart,
                                                   const int* __restrict__ kvals,
                                                   int* __restrict__ out, int qch) {
  const int slice = blockIdx.x, bh = blockIdx.y, t = threadIdx.x;
  __shared__ double s[MID];
  for (int j = t; j < MID; j += 256) {
    double v = 0.0;
    for (int qc = 0; qc < qch; ++qc)
      v += spart[((size_t)(qc * BH + bh)) * LKV + SINKN + j];
    s[j] = v;
  }
  __syncthreads();
  const int k = kvals[bh];
  const int JP = (MID + 7) / 8;   // 248
  const int j = slice * JP + t;
  if (t < JP && j < MID) {
    const double sj = s[j];
    int cnt = 0;
    for (int i = 0; i < j; ++i)       cnt += (s[i] >= sj) ? 1 : 0;
    for (int i = j + 1; i < MID; ++i) cnt += (s[i] >  sj) ? 1 : 0;
    out[(size_t)bh * LKV + SINKN + j] = (cnt < k) ? 1 : 0;
  }
  if (slice == 0) {
    if (t < SINKN)   out[(size_t)bh * LKV + t] = 1;
    if (t < RECENTN) out[(size_t)bh * LKV + (LKV - RECENTN) + t] = 1;
  }
}

extern "C" void kernel_launch(void* const* d_in, const int* in_sizes, int n_in,
                              void* d_out, int out_size, void* d_ws, size_t ws_size,
                              hipStream_t stream) {
  const float* A = (const float*)d_in[0];
  int* out = (int*)d_out;

  // Workspace: spart (qch*64*2048 f64) + epart (64*qch*KVCH f64) + kvals (64 int).
  int qch = 4;
  auto need = [](int q) {
    return (size_t)q * BH * LKV * sizeof(double) +
           (size_t)BH * q * KVCH * sizeof(double) + 256;
  };
  if (need(4) > ws_size) qch = (need(2) <= ws_size) ? 2 : 1;

  double* spart = (double*)d_ws;
  double* epart = spart + (size_t)qch * BH * LKV;
  int* kvals = (int*)(epart + (size_t)BH * qch * KVCH);

  stats_kernel<<<dim3(KVCH, qch, BH), 256, 0, stream>>>(A, spart, epart, qch);
  budget_kernel<<<1, 64, 0, stream>>>(epart, kvals, qch * KVCH);
  mask_kernel<<<dim3(8, BH), 256, 0, stream>>>(spart, kvals, out, qch);
}